// Round 4
// baseline (9889.361 us; speedup 1.0000x reference)
//
#include <hip/hip_runtime.h>
#include <hip/hip_bf16.h>
#include <hip/hip_fp16.h>

__device__ __forceinline__ float siluf(float x) {
    return x / (1.0f + __expf(-x));
}

// ---------------- init: species + s = W_embed[z], v = 0, deg = 0 ----------------
__global__ void k_init(const float* __restrict__ attrs, const float* __restrict__ Wemb,
                       int* __restrict__ species, int* __restrict__ deg,
                       float* __restrict__ s, float* __restrict__ v, int N) {
    int lane = threadIdx.x;
    int n0 = blockIdx.x * 64;
    for (int r = 0; r < 64; r++) {
        int n = n0 + r;
        if (n >= N) break;
        float a = (lane < 10) ? attrs[n * 10 + lane] : 0.0f;
        unsigned long long m = __ballot(a > 0.5f);
        int z = __ffsll(m) - 1;
        if (lane == 0) { species[n] = z; deg[n] = 0; }
        s[n * 64 + lane] = Wemb[z * 64 + lane];
        v[n * 192 + lane] = 0.0f;
        v[n * 192 + 64 + lane] = 0.0f;
        v[n * 192 + 128 + lane] = 0.0f;
    }
}

// ---------------- counting sort by receiver ----------------
__global__ void k_hist(const int* __restrict__ ei, int* __restrict__ deg, int E) {
    int e = blockIdx.x * 256 + threadIdx.x;
    if (e < E) atomicAdd(&deg[ei[E + e]], 1);
}

__global__ void k_scan(const int* __restrict__ deg, int* __restrict__ rowptr,
                       int* __restrict__ cursor, int N) {
    __shared__ int part[1024];
    int t = threadIdx.x;
    int chunk = (N + 1023) / 1024;
    int lo = t * chunk, hi = min(lo + chunk, N);
    int sum = 0;
    for (int i = lo; i < hi; i++) sum += deg[i];
    part[t] = sum;
    __syncthreads();
    for (int off = 1; off < 1024; off <<= 1) {
        int add = (t >= off) ? part[t - off] : 0;
        __syncthreads();
        part[t] += add;
        __syncthreads();
    }
    int run = (t > 0) ? part[t - 1] : 0;
    for (int i = lo; i < hi; i++) { rowptr[i] = run; cursor[i] = run; run += deg[i]; }
    if (t == 1023) rowptr[N] = part[1023];
}

__global__ void k_perm(const int* __restrict__ ei, int* __restrict__ cursor,
                       int* __restrict__ perm, int E) {
    int e = blockIdx.x * 256 + threadIdx.x;
    if (e < E) {
        int r = ei[E + e];
        int pos = atomicAdd(&cursor[r], 1);
        perm[pos] = e;
    }
}

// ---------------- geometry + radial basis on SORTED edge order ----------------
__global__ void k_geom(const int* __restrict__ ei, const int* __restrict__ perm,
                       const float* __restrict__ pos, const float* __restrict__ shifts,
                       float4* __restrict__ geo, float* __restrict__ efT,
                       int* __restrict__ snd_s, int E) {
    int j = blockIdx.x * 64 + threadIdx.x;
    if (j >= E) return;
    int e = perm[j];
    int snd = ei[e], rcv = ei[E + e];
    float dx = pos[rcv * 3 + 0] - pos[snd * 3 + 0] + shifts[e * 3 + 0];
    float dy = pos[rcv * 3 + 1] - pos[snd * 3 + 1] + shifts[e * 3 + 1];
    float dz = pos[rcv * 3 + 2] - pos[snd * 3 + 2] + shifts[e * 3 + 2];
    float r = sqrtf(dx * dx + dy * dy + dz * dz);
    float rin = 1.0f / (r + 1e-9f);
    const float SQ3 = 1.7320508075688772f;
    geo[j] = make_float4(SQ3 * dx * rin, SQ3 * dy * rin, SQ3 * dz * rin, 0.0f);
    snd_s[j] = snd;
    float u = r * 0.2f;
    float env = 0.0f;
    if (u < 1.0f) {
        float u2 = u * u;
        float u6 = u2 * u2 * u2;
        env = 1.0f - 28.0f * u6 + 48.0f * u6 * u - 21.0f * u6 * u2;
    }
    const float PIF = 3.14159265358979f;
    float x = PIF * u;
    float sp = __sinf(x), cp = __cosf(x);
    float coef = 0.6324555320336759f * rin * env;
    float sm1 = 0.0f, scur = sp, twoc = 2.0f * cp;
    #pragma unroll
    for (int k = 0; k < 8; k++) {
        efT[k * (size_t)E + j] = coef * scur;
        float nxt = twoc * scur - sm1;
        sm1 = scur; scur = nxt;
    }
}

// ---------------- generic 64-node tile GEMV ----------------
__device__ __forceinline__ void tile_mv64(const float* __restrict__ in, int istride,
                                          const float* __restrict__ W,
                                          float* __restrict__ outp, int ostride,
                                          float* __restrict__ packf, int comp,
                                          int n0, int nv, float* lds, int lane) {
    for (int r = 0; r < nv; r++) lds[r * 65 + lane] = in[(size_t)(n0 + r) * istride + lane];
    __syncthreads();
    float acc[64];
    #pragma unroll
    for (int d = 0; d < 64; d++) acc[d] = 0.0f;
    for (int c = 0; c < 64; c++) {
        float x = lds[lane * 65 + c];
        const float* wr = W + c * 64;
        #pragma unroll
        for (int d = 0; d < 64; d++) acc[d] = fmaf(x, wr[d], acc[d]);
    }
    __syncthreads();
    #pragma unroll
    for (int d = 0; d < 64; d++) lds[lane * 65 + d] = acc[d];
    __syncthreads();
    for (int r = 0; r < nv; r++) {
        float val = lds[r * 65 + lane];
        if (outp) outp[(size_t)(n0 + r) * ostride + lane] = val;
        if (packf) packf[(((size_t)(n0 + r)) * 64 + lane) * 4 + comp] = val;
    }
    __syncthreads();
}

// 4 GEMVs: s @ Ws and v[x] @ Wv; optionally into packed float4 layout
__global__ void k_4mv(const float* __restrict__ ins, const float* __restrict__ inv,
                      const float* __restrict__ Ws, const float* __restrict__ Wv,
                      float* __restrict__ outs, float* __restrict__ outv,
                      float* __restrict__ packf, int N) {
    __shared__ float lds[64 * 65];
    int lane = threadIdx.x;
    int n0 = blockIdx.x * 64;
    int nv = min(64, N - n0);
    tile_mv64(ins, 64, Ws, outs, 64, packf, 0, n0, nv, lds, lane);
    for (int x = 0; x < 3; x++)
        tile_mv64(inv + x * 64, 192, Wv, outv ? outv + x * 64 : nullptr, 192,
                  packf, 1 + x, n0, nv, lds, lane);
}

// ---------------- message kernel: register-resident MLP, no LDS, no barriers --------
__global__ __launch_bounds__(256, 3)
void k_msg(const int* __restrict__ rowptr, int na, int nb,
           const float* __restrict__ efT, const float4* __restrict__ geo,
           const int* __restrict__ snd_s, const float4* __restrict__ pack,
           const float* __restrict__ RW1, const float* __restrict__ RW2,
           const float* __restrict__ RW3, float2* __restrict__ msg,
           int cap, int E) {
    const int Jlo = rowptr[na], Jhi = rowptr[nb];
    const int j = Jlo + blockIdx.x * 256 + threadIdx.x;
    if (j >= Jhi) return;
    const int idx = j - Jlo;
    const bool live = (idx < cap);

    // ---- h1 = silu(ef @ RW1), registers ----
    float h1[64];
    #pragma unroll
    for (int d = 0; d < 64; d++) h1[d] = 0.0f;
    #pragma unroll
    for (int k = 0; k < 8; k++) {
        float x = efT[k * (size_t)E + j];
        const float* wr = RW1 + k * 64;
        #pragma unroll
        for (int d = 0; d < 64; d++) h1[d] = fmaf(x, wr[d], h1[d]);
    }
    #pragma unroll
    for (int d = 0; d < 64; d++) h1[d] = siluf(h1[d]);

    // ---- h2 = silu(h1 @ RW2), registers, fully unrolled ----
    float h2[64];
    #pragma unroll
    for (int d = 0; d < 64; d++) h2[d] = 0.0f;
    #pragma unroll
    for (int c = 0; c < 64; c++) {
        float x = h1[c];
        const float* wr = RW2 + c * 64;
        #pragma unroll
        for (int d = 0; d < 64; d++) h2[d] = fmaf(x, wr[d], h2[d]);
    }
    #pragma unroll
    for (int d = 0; d < 64; d++) h2[d] = siluf(h2[d]);

    const int snd = snd_s[j];
    const float4 g = geo[j];
    const float4* __restrict__ prow = pack + (size_t)snd * 64;
    float2* __restrict__ mrow = msg + (size_t)idx * 64;

    const float inv32 = 1.0f / 32.0f;
    const float is3 = 0.5773502691896258f;   // 1/sqrt(3)
    const float is2 = 0.7071067811865476f;   // 1/sqrt(2)

    // ---- w = h2 @ RW3 in chunks of 8 channels, then messages ----
    for (int cc = 0; cc < 8; cc++) {
        float w[40];
        #pragma unroll
        for (int q = 0; q < 40; q++) w[q] = 0.0f;
        #pragma unroll
        for (int c = 0; c < 64; c++) {
            float x = h2[c];
            const float* wr = RW3 + c * 320 + cc * 8;
            #pragma unroll
            for (int q = 0; q < 5; q++) {
                #pragma unroll
                for (int jj = 0; jj < 8; jj++)
                    w[q * 8 + jj] = fmaf(x, wr[q * 64 + jj], w[q * 8 + jj]);
            }
        }
        #pragma unroll
        for (int jj = 0; jj < 8; jj++) {
            const int c = cc * 8 + jj;
            float4 pv = prow[c];  // (s_up, v0, v1, v2) of sender
            float w00  = w[jj];
            float w110 = w[8 + jj];
            float w011 = w[16 + jj];
            float w101 = w[24 + jj];
            float w111 = w[32 + jj];
            float dvy = pv.y * g.x + pv.z * g.y + pv.w * g.z;
            float m0 = (w00 * pv.x + w110 * dvy * is3) * inv32;
            float cxv = pv.z * g.z - pv.w * g.y;
            float cyv = pv.w * g.x - pv.y * g.z;
            float czv = pv.y * g.y - pv.z * g.x;
            float m1x = (w011 * pv.x * g.x + w101 * pv.y + w111 * cxv * is2) * inv32;
            float m1y = (w011 * pv.x * g.y + w101 * pv.z + w111 * cyv * is2) * inv32;
            float m1z = (w011 * pv.x * g.z + w101 * pv.w + w111 * czv * is2) * inv32;
            union { __half2 h; float f; } ua, ub;
            ua.h = __floats2half2_rn(m0, m1x);
            ub.h = __floats2half2_rn(m1y, m1z);
            if (live) mrow[c] = make_float2(ua.f, ub.f);
        }
    }
}

// ---------------- CSR aggregation: wave per node, lane = channel ----------------
__global__ void k_agg(const float2* __restrict__ msg, const int* __restrict__ rowptr,
                      float* __restrict__ agg0, float* __restrict__ agg1,
                      int na, int nb, int cap) {
    int n = na + blockIdx.x * 4 + (threadIdx.x >> 6);
    int lane = threadIdx.x & 63;
    if (n >= nb) return;
    int Jlo = rowptr[na];
    int j0 = rowptr[n], j1 = rowptr[n + 1];
    float a0 = 0.0f, a1 = 0.0f, a2 = 0.0f, a3 = 0.0f;
    for (int j = j0; j < j1; j++) {
        int idx = j - Jlo;
        if (idx >= cap) break;
        float2 m = msg[(size_t)idx * 64 + lane];
        union { float f; __half2 h; } ua, ub;
        ua.f = m.x; ub.f = m.y;
        float2 fa = __half22float2(ua.h);
        float2 fb = __half22float2(ub.h);
        a0 += fa.x; a1 += fa.y; a2 += fb.x; a3 += fb.y;
    }
    size_t nbase = (size_t)n;
    agg0[nbase * 64 + lane] = a0;
    agg1[nbase * 192 + lane] = a1;
    agg1[nbase * 192 + 64 + lane] = a2;
    agg1[nbase * 192 + 128 + lane] = a3;
}

// ---------------- species-dependent skip connections (wave = node) ----------------
__global__ void k_sc(const float* __restrict__ s, const float* __restrict__ v,
                     const int* __restrict__ species, const float* __restrict__ Wsc_s,
                     const float* __restrict__ Wsc_v, float* __restrict__ sc_s,
                     float* __restrict__ sc_v, int N) {
    int n = blockIdx.x;
    if (n >= N) return;
    int lane = threadIdx.x;
    int z = species[n];
    const float* Ws = Wsc_s + (size_t)z * 4096;
    const float* Wv = Wsc_v + (size_t)z * 4096;
    size_t nb = (size_t)n;
    float sreg = s[nb * 64 + lane];
    float acc = 0.0f;
    for (int c = 0; c < 64; c++)
        acc = fmaf(__shfl(sreg, c), Ws[c * 64 + lane], acc);
    sc_s[nb * 64 + lane] = acc;
    for (int x = 0; x < 3; x++) {
        float vreg = v[nb * 192 + x * 64 + lane];
        float av = 0.0f;
        for (int c = 0; c < 64; c++)
            av = fmaf(__shfl(vreg, c), Wv[c * 64 + lane], av);
        sc_v[nb * 192 + x * 64 + lane] = av;
    }
}

// ---------------- prod_s -> new s + output slot ----------------
__global__ void k_prod_s(const float* __restrict__ ms, const float* __restrict__ mv,
                         const float* __restrict__ P0l, const int* __restrict__ species,
                         const float* __restrict__ Wp, const float* __restrict__ sc_s,
                         float* __restrict__ s, float* __restrict__ out,
                         int N, int layer, int L) {
    __shared__ float lds[64 * 65];
    int lane = threadIdx.x;
    int n0 = blockIdx.x * 64;
    int nv = min(64, N - n0);
    for (int r = 0; r < nv; r++) {
        size_t n = n0 + r;
        int z = species[n];
        float msv = ms[n * 64 + lane];
        float a = mv[n * 192 + lane];
        float b = mv[n * 192 + 64 + lane];
        float cq = mv[n * 192 + 128 + lane];
        float mq = a * a + b * b + cq * cq;
        const float* p = P0l + ((size_t)z * 64 + lane) * 3;
        lds[r * 65 + lane] = p[0] * msv + p[1] * msv * msv + p[2] * mq;
    }
    __syncthreads();
    float acc[64];
    #pragma unroll
    for (int d = 0; d < 64; d++) acc[d] = 0.0f;
    for (int c = 0; c < 64; c++) {
        float x = lds[lane * 65 + c];
        const float* wr = Wp + c * 64;
        #pragma unroll
        for (int d = 0; d < 64; d++) acc[d] = fmaf(x, wr[d], acc[d]);
    }
    __syncthreads();
    #pragma unroll
    for (int d = 0; d < 64; d++) lds[lane * 65 + d] = acc[d];
    __syncthreads();
    for (int r = 0; r < nv; r++) {
        size_t n = n0 + r;
        float val = lds[r * 65 + lane] + sc_s[n * 64 + lane];
        s[n * 64 + lane] = val;
        out[n * (size_t)(L * 64) + layer * 64 + lane] = val;
    }
}

// ---------------- prod_v -> new v ----------------
__global__ void k_prod_v(const float* __restrict__ ms, const float* __restrict__ mv,
                         const float* __restrict__ P1l, const int* __restrict__ species,
                         const float* __restrict__ Wp, const float* __restrict__ sc_v,
                         float* __restrict__ v, int N) {
    __shared__ float lds[64 * 65];
    int lane = threadIdx.x;
    int n0 = blockIdx.x * 64;
    int nv = min(64, N - n0);
    for (int x = 0; x < 3; x++) {
        for (int r = 0; r < nv; r++) {
            size_t n = n0 + r;
            int z = species[n];
            float msv = ms[n * 64 + lane];
            float mvv = mv[n * 192 + x * 64 + lane];
            const float* q = P1l + ((size_t)z * 64 + lane) * 2;
            lds[r * 65 + lane] = (q[0] + q[1] * msv) * mvv;
        }
        __syncthreads();
        float acc[64];
        #pragma unroll
        for (int d = 0; d < 64; d++) acc[d] = 0.0f;
        for (int c = 0; c < 64; c++) {
            float xx = lds[lane * 65 + c];
            const float* wr = Wp + c * 64;
            #pragma unroll
            for (int d = 0; d < 64; d++) acc[d] = fmaf(xx, wr[d], acc[d]);
        }
        __syncthreads();
        #pragma unroll
        for (int d = 0; d < 64; d++) lds[lane * 65 + d] = acc[d];
        __syncthreads();
        for (int r = 0; r < nv; r++) {
            size_t n = n0 + r;
            v[n * 192 + x * 64 + lane] = lds[r * 65 + lane] + sc_v[n * 192 + x * 64 + lane];
        }
        __syncthreads();
    }
}

extern "C" void kernel_launch(void* const* d_in, const int* in_sizes, int n_in,
                              void* d_out, int out_size, void* d_ws, size_t ws_size,
                              hipStream_t stream) {
    const float* node_attrs = (const float*)d_in[0];
    const float* atom_pos   = (const float*)d_in[1];
    const float* shifts     = (const float*)d_in[2];
    const float* W_embed    = (const float*)d_in[3];
    const float* Wup_s      = (const float*)d_in[4];
    const float* Wup_v      = (const float*)d_in[5];
    const float* RW1        = (const float*)d_in[6];
    const float* RW2        = (const float*)d_in[7];
    const float* RW3        = (const float*)d_in[8];
    const float* Wout_s     = (const float*)d_in[9];
    const float* Wout_v     = (const float*)d_in[10];
    const float* Wsc_s      = (const float*)d_in[11];
    const float* Wsc_v      = (const float*)d_in[12];
    const float* P0         = (const float*)d_in[13];
    const float* P1         = (const float*)d_in[14];
    const float* Wprod_s    = (const float*)d_in[15];
    const float* Wprod_v    = (const float*)d_in[16];
    const int*   ei         = (const int*)d_in[17];

    const int N = in_sizes[0] / 10;
    const int E = in_sizes[17] / 2;
    const int L = in_sizes[4] / 4096;
    float* out = (float*)d_out;

    char* wsb = (char*)d_ws;
    size_t off = 0;
    auto alloci = [&](size_t n) {
        int* p = (int*)(wsb + off);
        off = (off + n * 4 + 255) / 256 * 256;
        return p;
    };
    auto allocf = [&](size_t n) {
        float* p = (float*)(wsb + off);
        off = (off + n * 4 + 255) / 256 * 256;
        return p;
    };
    int* species = alloci(N);
    int* deg     = alloci(N);
    int* rowptr  = alloci(N + 1);
    int* cursor  = alloci(N);
    int* perm    = alloci(E);
    int* snd_s   = alloci(E);
    float* s     = allocf((size_t)N * 64);
    float* v     = allocf((size_t)N * 192);
    float* agg0  = allocf((size_t)N * 64);   // reused in-place as ms
    float* agg1  = allocf((size_t)N * 192);  // reused in-place as mv
    float* geo   = allocf((size_t)E * 4);
    float* efT   = allocf((size_t)E * 8);
    float* pack  = allocf((size_t)N * 256);
    // sc_s/sc_v alias pack (lifetimes disjoint within a layer)
    float* sc_s  = pack;
    float* sc_v  = pack + (size_t)N * 64;

    // pick NCHUNK at runtime from ws_size (constant per session -> graph-safe)
    int NCHUNK = 16;
    int cap = 0;
    {
        const int cands[8] = {1, 2, 3, 4, 6, 8, 12, 16};
        for (int ci = 0; ci < 8; ci++) {
            int c = cands[ci];
            int thiscap = (c == 1) ? E : (E / c) * 5 / 4 + 256;
            size_t need = off + (size_t)thiscap * 512;  // 128 floats * 4B per edge
            if (need <= ws_size) { NCHUNK = c; cap = thiscap; break; }
        }
        if (cap == 0) { NCHUNK = 16; cap = (E / 16) * 5 / 4 + 256; }
    }
    float* msg = allocf((size_t)cap * 128);   // fp16 half4 = float2 per (edge,ch)
    (void)n_in; (void)out_size;

    const int NT = (N + 63) / 64;
    const int ET = (E + 63) / 64;
    const int EB = (E + 255) / 256;
    const int MT = (cap + 255) / 256;          // k_msg grid per chunk

    k_init<<<NT, 64, 0, stream>>>(node_attrs, W_embed, species, deg, s, v, N);
    k_hist<<<EB, 256, 0, stream>>>(ei, deg, E);
    k_scan<<<1, 1024, 0, stream>>>(deg, rowptr, cursor, N);
    k_perm<<<EB, 256, 0, stream>>>(ei, cursor, perm, E);
    k_geom<<<ET, 64, 0, stream>>>(ei, perm, atom_pos, shifts,
                                  (float4*)geo, efT, snd_s, E);

    int nbound[17];
    for (int k = 0; k <= NCHUNK; k++) nbound[k] = (int)((long long)N * k / NCHUNK);

    for (int i = 0; i < L; i++) {
        k_4mv<<<NT, 64, 0, stream>>>(s, v, Wup_s + (size_t)i * 4096, Wup_v + (size_t)i * 4096,
                                     nullptr, nullptr, pack, N);
        for (int k = 0; k < NCHUNK; k++) {
            int na = nbound[k], nb = nbound[k + 1];
            k_msg<<<MT, 256, 0, stream>>>(rowptr, na, nb, efT, (const float4*)geo, snd_s,
                                          (const float4*)pack,
                                          RW1 + (size_t)i * 512, RW2 + (size_t)i * 4096,
                                          RW3 + (size_t)i * 20480, (float2*)msg, cap, E);
            int cnt = nb - na;
            k_agg<<<(cnt + 3) / 4, 256, 0, stream>>>((const float2*)msg, rowptr,
                                                     agg0, agg1, na, nb, cap);
        }
        k_sc<<<N, 64, 0, stream>>>(s, v, species, Wsc_s + (size_t)i * 40960,
                                   Wsc_v + (size_t)i * 40960, sc_s, sc_v, N);
        k_4mv<<<NT, 64, 0, stream>>>(agg0, agg1, Wout_s + (size_t)i * 4096,
                                     Wout_v + (size_t)i * 4096, agg0, agg1, nullptr, N);
        k_prod_s<<<NT, 64, 0, stream>>>(agg0, agg1, P0 + (size_t)i * 1920, species,
                                        Wprod_s + (size_t)i * 4096, sc_s, s, out, N, i, L);
        k_prod_v<<<NT, 64, 0, stream>>>(agg0, agg1, P1 + (size_t)i * 1280, species,
                                        Wprod_v + (size_t)i * 4096, sc_v, v, N);
    }
}

// Round 5
// 2170.793 us; speedup vs baseline: 4.5556x; 4.5556x over previous
//
#include <hip/hip_runtime.h>
#include <hip/hip_bf16.h>
#include <hip/hip_fp16.h>

__device__ __forceinline__ float siluf(float x) {
    return x / (1.0f + __expf(-x));
}

// ---------------- init: species + s = W_embed[z], v = 0, deg = 0 ----------------
__global__ void k_init(const float* __restrict__ attrs, const float* __restrict__ Wemb,
                       int* __restrict__ species, int* __restrict__ deg,
                       float* __restrict__ s, float* __restrict__ v, int N) {
    int lane = threadIdx.x;
    int n0 = blockIdx.x * 64;
    for (int r = 0; r < 64; r++) {
        int n = n0 + r;
        if (n >= N) break;
        float a = (lane < 10) ? attrs[n * 10 + lane] : 0.0f;
        unsigned long long m = __ballot(a > 0.5f);
        int z = __ffsll(m) - 1;
        if (lane == 0) { species[n] = z; deg[n] = 0; }
        s[n * 64 + lane] = Wemb[z * 64 + lane];
        v[n * 192 + lane] = 0.0f;
        v[n * 192 + 64 + lane] = 0.0f;
        v[n * 192 + 128 + lane] = 0.0f;
    }
}

// ---------------- counting sort by receiver ----------------
__global__ void k_hist(const int* __restrict__ ei, int* __restrict__ deg, int E) {
    int e = blockIdx.x * 256 + threadIdx.x;
    if (e < E) atomicAdd(&deg[ei[E + e]], 1);
}

__global__ void k_scan(const int* __restrict__ deg, int* __restrict__ rowptr,
                       int* __restrict__ cursor, int N) {
    __shared__ int part[1024];
    int t = threadIdx.x;
    int chunk = (N + 1023) / 1024;
    int lo = t * chunk, hi = min(lo + chunk, N);
    int sum = 0;
    for (int i = lo; i < hi; i++) sum += deg[i];
    part[t] = sum;
    __syncthreads();
    for (int off = 1; off < 1024; off <<= 1) {
        int add = (t >= off) ? part[t - off] : 0;
        __syncthreads();
        part[t] += add;
        __syncthreads();
    }
    int run = (t > 0) ? part[t - 1] : 0;
    for (int i = lo; i < hi; i++) { rowptr[i] = run; cursor[i] = run; run += deg[i]; }
    if (t == 1023) rowptr[N] = part[1023];
}

__global__ void k_perm(const int* __restrict__ ei, int* __restrict__ cursor,
                       int* __restrict__ perm, int E) {
    int e = blockIdx.x * 256 + threadIdx.x;
    if (e < E) {
        int r = ei[E + e];
        int pos = atomicAdd(&cursor[r], 1);
        perm[pos] = e;
    }
}

// ---------------- geometry + radial basis on SORTED edge order ----------------
__global__ void k_geom(const int* __restrict__ ei, const int* __restrict__ perm,
                       const float* __restrict__ pos, const float* __restrict__ shifts,
                       float4* __restrict__ geo, float* __restrict__ efT,
                       int* __restrict__ snd_s, int E) {
    int j = blockIdx.x * 64 + threadIdx.x;
    if (j >= E) return;
    int e = perm[j];
    int snd = ei[e], rcv = ei[E + e];
    float dx = pos[rcv * 3 + 0] - pos[snd * 3 + 0] + shifts[e * 3 + 0];
    float dy = pos[rcv * 3 + 1] - pos[snd * 3 + 1] + shifts[e * 3 + 1];
    float dz = pos[rcv * 3 + 2] - pos[snd * 3 + 2] + shifts[e * 3 + 2];
    float r = sqrtf(dx * dx + dy * dy + dz * dz);
    float rin = 1.0f / (r + 1e-9f);
    const float SQ3 = 1.7320508075688772f;
    geo[j] = make_float4(SQ3 * dx * rin, SQ3 * dy * rin, SQ3 * dz * rin, 0.0f);
    snd_s[j] = snd;
    float u = r * 0.2f;
    float env = 0.0f;
    if (u < 1.0f) {
        float u2 = u * u;
        float u6 = u2 * u2 * u2;
        env = 1.0f - 28.0f * u6 + 48.0f * u6 * u - 21.0f * u6 * u2;
    }
    const float PIF = 3.14159265358979f;
    float x = PIF * u;
    float sp = __sinf(x), cp = __cosf(x);
    float coef = 0.6324555320336759f * rin * env;
    float sm1 = 0.0f, scur = sp, twoc = 2.0f * cp;
    #pragma unroll
    for (int k = 0; k < 8; k++) {
        efT[k * (size_t)E + j] = coef * scur;
        float nxt = twoc * scur - sm1;
        sm1 = scur; scur = nxt;
    }
}

// ---------------- generic 64-node tile GEMV ----------------
__device__ __forceinline__ void tile_mv64(const float* __restrict__ in, int istride,
                                          const float* __restrict__ W,
                                          float* __restrict__ outp, int ostride,
                                          float* __restrict__ packf, int comp,
                                          int n0, int nv, float* lds, int lane) {
    for (int r = 0; r < nv; r++) lds[r * 65 + lane] = in[(size_t)(n0 + r) * istride + lane];
    __syncthreads();
    float acc[64];
    #pragma unroll
    for (int d = 0; d < 64; d++) acc[d] = 0.0f;
    for (int c = 0; c < 64; c++) {
        float x = lds[lane * 65 + c];
        const float* wr = W + c * 64;
        #pragma unroll
        for (int d = 0; d < 64; d++) acc[d] = fmaf(x, wr[d], acc[d]);
    }
    __syncthreads();
    #pragma unroll
    for (int d = 0; d < 64; d++) lds[lane * 65 + d] = acc[d];
    __syncthreads();
    for (int r = 0; r < nv; r++) {
        float val = lds[r * 65 + lane];
        if (outp) outp[(size_t)(n0 + r) * ostride + lane] = val;
        if (packf) packf[(((size_t)(n0 + r)) * 64 + lane) * 4 + comp] = val;
    }
    __syncthreads();
}

// 4 GEMVs: s @ Ws and v[x] @ Wv; optionally into packed float4 layout
__global__ void k_4mv(const float* __restrict__ ins, const float* __restrict__ inv,
                      const float* __restrict__ Ws, const float* __restrict__ Wv,
                      float* __restrict__ outs, float* __restrict__ outv,
                      float* __restrict__ packf, int N) {
    __shared__ float lds[64 * 65];
    int lane = threadIdx.x;
    int n0 = blockIdx.x * 64;
    int nv = min(64, N - n0);
    tile_mv64(ins, 64, Ws, outs, 64, packf, 0, n0, nv, lds, lane);
    for (int x = 0; x < 3; x++)
        tile_mv64(inv + x * 64, 192, Wv, outv ? outv + x * 64 : nullptr, 192,
                  packf, 1 + x, n0, nv, lds, lane);
}

// ---------------- message kernel: h1 in regs, h2 fp16 in private LDS column ----------
// No __syncthreads (each thread touches only its own LDS column). Peak live regs ~90.
__global__ __launch_bounds__(256, 4)
void k_msg(const int* __restrict__ rowptr, int na, int nb,
           const float* __restrict__ efT, const float4* __restrict__ geo,
           const int* __restrict__ snd_s, const float4* __restrict__ pack,
           const float* __restrict__ RW1, const float* __restrict__ RW2,
           const float* __restrict__ RW3, float2* __restrict__ msg,
           int cap, int E) {
    __shared__ __half2 lh2[32 * 256];        // h2 as half2: [c2][tid], 32 KB
    const int tid = threadIdx.x;
    const int Jlo = rowptr[na], Jhi = rowptr[nb];
    const int j = Jlo + blockIdx.x * 256 + tid;
    if (j >= Jhi) return;
    const int idx = j - Jlo;
    const bool live = (idx < cap);

    // ---- h1 = silu(ef @ RW1), registers (64 live) ----
    float h1[64];
    #pragma unroll
    for (int d = 0; d < 64; d++) h1[d] = 0.0f;
    #pragma unroll
    for (int k = 0; k < 8; k++) {
        float x = efT[k * (size_t)E + j];
        const float* wr = RW1 + k * 64;
        #pragma unroll
        for (int d = 0; d < 64; d++) h1[d] = fmaf(x, wr[d], h1[d]);
    }
    #pragma unroll
    for (int d = 0; d < 64; d++) h1[d] = siluf(h1[d]);

    // ---- h2 = silu(h1 @ RW2), 16 channels at a time -> fp16 LDS ----
    for (int dc = 0; dc < 4; dc++) {
        float t[16];
        #pragma unroll
        for (int q = 0; q < 16; q++) t[q] = 0.0f;
        #pragma unroll
        for (int c = 0; c < 64; c++) {
            float x = h1[c];
            const float* wr = RW2 + c * 64 + dc * 16;
            #pragma unroll
            for (int q = 0; q < 16; q++) t[q] = fmaf(x, wr[q], t[q]);
        }
        #pragma unroll
        for (int p = 0; p < 8; p++) {
            float a = siluf(t[2 * p]);
            float b = siluf(t[2 * p + 1]);
            lh2[(dc * 8 + p) * 256 + tid] = __floats2half2_rn(a, b);
        }
    }

    const int snd = snd_s[j];
    const float4 g = geo[j];
    const float4* __restrict__ prow = pack + (size_t)snd * 64;
    float2* __restrict__ mrow = msg + (size_t)idx * 64;

    const float inv32 = 1.0f / 32.0f;
    const float is3 = 0.5773502691896258f;   // 1/sqrt(3)
    const float is2 = 0.7071067811865476f;   // 1/sqrt(2)

    // ---- w = h2 @ RW3 in chunks of 8 channels, then messages ----
    for (int cc = 0; cc < 8; cc++) {
        float w[40];
        #pragma unroll
        for (int q = 0; q < 40; q++) w[q] = 0.0f;
        for (int c2 = 0; c2 < 32; c2++) {
            float2 f = __half22float2(lh2[c2 * 256 + tid]);
            const float* wr0 = RW3 + (2 * c2) * 320 + cc * 8;
            const float* wr1 = wr0 + 320;
            #pragma unroll
            for (int q = 0; q < 5; q++) {
                #pragma unroll
                for (int jj = 0; jj < 8; jj++) {
                    w[q * 8 + jj] = fmaf(f.x, wr0[q * 64 + jj], w[q * 8 + jj]);
                    w[q * 8 + jj] = fmaf(f.y, wr1[q * 64 + jj], w[q * 8 + jj]);
                }
            }
        }
        #pragma unroll
        for (int jj = 0; jj < 8; jj++) {
            const int c = cc * 8 + jj;
            float4 pv = prow[c];  // (s_up, v0, v1, v2) of sender
            float w00  = w[jj];
            float w110 = w[8 + jj];
            float w011 = w[16 + jj];
            float w101 = w[24 + jj];
            float w111 = w[32 + jj];
            float dvy = pv.y * g.x + pv.z * g.y + pv.w * g.z;
            float m0 = (w00 * pv.x + w110 * dvy * is3) * inv32;
            float cxv = pv.z * g.z - pv.w * g.y;
            float cyv = pv.w * g.x - pv.y * g.z;
            float czv = pv.y * g.y - pv.z * g.x;
            float m1x = (w011 * pv.x * g.x + w101 * pv.y + w111 * cxv * is2) * inv32;
            float m1y = (w011 * pv.x * g.y + w101 * pv.z + w111 * cyv * is2) * inv32;
            float m1z = (w011 * pv.x * g.z + w101 * pv.w + w111 * czv * is2) * inv32;
            union { __half2 h; float f; } ua, ub;
            ua.h = __floats2half2_rn(m0, m1x);
            ub.h = __floats2half2_rn(m1y, m1z);
            if (live) mrow[c] = make_float2(ua.f, ub.f);
        }
    }
}

// ---------------- CSR aggregation: wave per node, lane = channel ----------------
__global__ void k_agg(const float2* __restrict__ msg, const int* __restrict__ rowptr,
                      float* __restrict__ agg0, float* __restrict__ agg1,
                      int na, int nb, int cap) {
    int n = na + blockIdx.x * 4 + (threadIdx.x >> 6);
    int lane = threadIdx.x & 63;
    if (n >= nb) return;
    int Jlo = rowptr[na];
    int j0 = rowptr[n], j1 = rowptr[n + 1];
    float a0 = 0.0f, a1 = 0.0f, a2 = 0.0f, a3 = 0.0f;
    for (int j = j0; j < j1; j++) {
        int idx = j - Jlo;
        if (idx >= cap) break;
        float2 m = msg[(size_t)idx * 64 + lane];
        union { float f; __half2 h; } ua, ub;
        ua.f = m.x; ub.f = m.y;
        float2 fa = __half22float2(ua.h);
        float2 fb = __half22float2(ub.h);
        a0 += fa.x; a1 += fa.y; a2 += fb.x; a3 += fb.y;
    }
    size_t nbase = (size_t)n;
    agg0[nbase * 64 + lane] = a0;
    agg1[nbase * 192 + lane] = a1;
    agg1[nbase * 192 + 64 + lane] = a2;
    agg1[nbase * 192 + 128 + lane] = a3;
}

// ---------------- species-dependent skip connections (wave = node) ----------------
__global__ void k_sc(const float* __restrict__ s, const float* __restrict__ v,
                     const int* __restrict__ species, const float* __restrict__ Wsc_s,
                     const float* __restrict__ Wsc_v, float* __restrict__ sc_s,
                     float* __restrict__ sc_v, int N) {
    int n = blockIdx.x;
    if (n >= N) return;
    int lane = threadIdx.x;
    int z = species[n];
    const float* Ws = Wsc_s + (size_t)z * 4096;
    const float* Wv = Wsc_v + (size_t)z * 4096;
    size_t nb = (size_t)n;
    float sreg = s[nb * 64 + lane];
    float acc = 0.0f;
    for (int c = 0; c < 64; c++)
        acc = fmaf(__shfl(sreg, c), Ws[c * 64 + lane], acc);
    sc_s[nb * 64 + lane] = acc;
    for (int x = 0; x < 3; x++) {
        float vreg = v[nb * 192 + x * 64 + lane];
        float av = 0.0f;
        for (int c = 0; c < 64; c++)
            av = fmaf(__shfl(vreg, c), Wv[c * 64 + lane], av);
        sc_v[nb * 192 + x * 64 + lane] = av;
    }
}

// ---------------- prod_s -> new s + output slot ----------------
__global__ void k_prod_s(const float* __restrict__ ms, const float* __restrict__ mv,
                         const float* __restrict__ P0l, const int* __restrict__ species,
                         const float* __restrict__ Wp, const float* __restrict__ sc_s,
                         float* __restrict__ s, float* __restrict__ out,
                         int N, int layer, int L) {
    __shared__ float lds[64 * 65];
    int lane = threadIdx.x;
    int n0 = blockIdx.x * 64;
    int nv = min(64, N - n0);
    for (int r = 0; r < nv; r++) {
        size_t n = n0 + r;
        int z = species[n];
        float msv = ms[n * 64 + lane];
        float a = mv[n * 192 + lane];
        float b = mv[n * 192 + 64 + lane];
        float cq = mv[n * 192 + 128 + lane];
        float mq = a * a + b * b + cq * cq;
        const float* p = P0l + ((size_t)z * 64 + lane) * 3;
        lds[r * 65 + lane] = p[0] * msv + p[1] * msv * msv + p[2] * mq;
    }
    __syncthreads();
    float acc[64];
    #pragma unroll
    for (int d = 0; d < 64; d++) acc[d] = 0.0f;
    for (int c = 0; c < 64; c++) {
        float x = lds[lane * 65 + c];
        const float* wr = Wp + c * 64;
        #pragma unroll
        for (int d = 0; d < 64; d++) acc[d] = fmaf(x, wr[d], acc[d]);
    }
    __syncthreads();
    #pragma unroll
    for (int d = 0; d < 64; d++) lds[lane * 65 + d] = acc[d];
    __syncthreads();
    for (int r = 0; r < nv; r++) {
        size_t n = n0 + r;
        float val = lds[r * 65 + lane] + sc_s[n * 64 + lane];
        s[n * 64 + lane] = val;
        out[n * (size_t)(L * 64) + layer * 64 + lane] = val;
    }
}

// ---------------- prod_v -> new v ----------------
__global__ void k_prod_v(const float* __restrict__ ms, const float* __restrict__ mv,
                         const float* __restrict__ P1l, const int* __restrict__ species,
                         const float* __restrict__ Wp, const float* __restrict__ sc_v,
                         float* __restrict__ v, int N) {
    __shared__ float lds[64 * 65];
    int lane = threadIdx.x;
    int n0 = blockIdx.x * 64;
    int nv = min(64, N - n0);
    for (int x = 0; x < 3; x++) {
        for (int r = 0; r < nv; r++) {
            size_t n = n0 + r;
            int z = species[n];
            float msv = ms[n * 64 + lane];
            float mvv = mv[n * 192 + x * 64 + lane];
            const float* q = P1l + ((size_t)z * 64 + lane) * 2;
            lds[r * 65 + lane] = (q[0] + q[1] * msv) * mvv;
        }
        __syncthreads();
        float acc[64];
        #pragma unroll
        for (int d = 0; d < 64; d++) acc[d] = 0.0f;
        for (int c = 0; c < 64; c++) {
            float xx = lds[lane * 65 + c];
            const float* wr = Wp + c * 64;
            #pragma unroll
            for (int d = 0; d < 64; d++) acc[d] = fmaf(xx, wr[d], acc[d]);
        }
        __syncthreads();
        #pragma unroll
        for (int d = 0; d < 64; d++) lds[lane * 65 + d] = acc[d];
        __syncthreads();
        for (int r = 0; r < nv; r++) {
            size_t n = n0 + r;
            v[n * 192 + x * 64 + lane] = lds[r * 65 + lane] + sc_v[n * 192 + x * 64 + lane];
        }
        __syncthreads();
    }
}

extern "C" void kernel_launch(void* const* d_in, const int* in_sizes, int n_in,
                              void* d_out, int out_size, void* d_ws, size_t ws_size,
                              hipStream_t stream) {
    const float* node_attrs = (const float*)d_in[0];
    const float* atom_pos   = (const float*)d_in[1];
    const float* shifts     = (const float*)d_in[2];
    const float* W_embed    = (const float*)d_in[3];
    const float* Wup_s      = (const float*)d_in[4];
    const float* Wup_v      = (const float*)d_in[5];
    const float* RW1        = (const float*)d_in[6];
    const float* RW2        = (const float*)d_in[7];
    const float* RW3        = (const float*)d_in[8];
    const float* Wout_s     = (const float*)d_in[9];
    const float* Wout_v     = (const float*)d_in[10];
    const float* Wsc_s      = (const float*)d_in[11];
    const float* Wsc_v      = (const float*)d_in[12];
    const float* P0         = (const float*)d_in[13];
    const float* P1         = (const float*)d_in[14];
    const float* Wprod_s    = (const float*)d_in[15];
    const float* Wprod_v    = (const float*)d_in[16];
    const int*   ei         = (const int*)d_in[17];

    const int N = in_sizes[0] / 10;
    const int E = in_sizes[17] / 2;
    const int L = in_sizes[4] / 4096;
    float* out = (float*)d_out;

    char* wsb = (char*)d_ws;
    size_t off = 0;
    auto alloci = [&](size_t n) {
        int* p = (int*)(wsb + off);
        off = (off + n * 4 + 255) / 256 * 256;
        return p;
    };
    auto allocf = [&](size_t n) {
        float* p = (float*)(wsb + off);
        off = (off + n * 4 + 255) / 256 * 256;
        return p;
    };
    int* species = alloci(N);
    int* deg     = alloci(N);
    int* rowptr  = alloci(N + 1);
    int* cursor  = alloci(N);
    int* perm    = alloci(E);
    int* snd_s   = alloci(E);
    float* s     = allocf((size_t)N * 64);
    float* v     = allocf((size_t)N * 192);
    float* agg0  = allocf((size_t)N * 64);   // reused in-place as ms
    float* agg1  = allocf((size_t)N * 192);  // reused in-place as mv
    float* geo   = allocf((size_t)E * 4);
    float* efT   = allocf((size_t)E * 8);
    float* pack  = allocf((size_t)N * 256);
    // sc_s/sc_v alias pack (lifetimes disjoint within a layer)
    float* sc_s  = pack;
    float* sc_v  = pack + (size_t)N * 64;

    // pick NCHUNK at runtime from ws_size (constant per session -> graph-safe)
    int NCHUNK = 16;
    int cap = 0;
    {
        const int cands[8] = {1, 2, 3, 4, 6, 8, 12, 16};
        for (int ci = 0; ci < 8; ci++) {
            int c = cands[ci];
            int thiscap = (c == 1) ? E : (E / c) * 5 / 4 + 256;
            size_t need = off + (size_t)thiscap * 512;  // 128 floats * 4B per edge
            if (need <= ws_size) { NCHUNK = c; cap = thiscap; break; }
        }
        if (cap == 0) { NCHUNK = 16; cap = (E / 16) * 5 / 4 + 256; }
    }
    float* msg = allocf((size_t)cap * 128);   // fp16 half4 = float2 per (edge,ch)
    (void)n_in; (void)out_size;

    const int NT = (N + 63) / 64;
    const int ET = (E + 63) / 64;
    const int EB = (E + 255) / 256;
    const int MT = (cap + 255) / 256;          // k_msg grid per chunk

    k_init<<<NT, 64, 0, stream>>>(node_attrs, W_embed, species, deg, s, v, N);
    k_hist<<<EB, 256, 0, stream>>>(ei, deg, E);
    k_scan<<<1, 1024, 0, stream>>>(deg, rowptr, cursor, N);
    k_perm<<<EB, 256, 0, stream>>>(ei, cursor, perm, E);
    k_geom<<<ET, 64, 0, stream>>>(ei, perm, atom_pos, shifts,
                                  (float4*)geo, efT, snd_s, E);

    int nbound[17];
    for (int k = 0; k <= NCHUNK; k++) nbound[k] = (int)((long long)N * k / NCHUNK);

    for (int i = 0; i < L; i++) {
        k_4mv<<<NT, 64, 0, stream>>>(s, v, Wup_s + (size_t)i * 4096, Wup_v + (size_t)i * 4096,
                                     nullptr, nullptr, pack, N);
        for (int k = 0; k < NCHUNK; k++) {
            int na = nbound[k], nb = nbound[k + 1];
            k_msg<<<MT, 256, 0, stream>>>(rowptr, na, nb, efT, (const float4*)geo, snd_s,
                                          (const float4*)pack,
                                          RW1 + (size_t)i * 512, RW2 + (size_t)i * 4096,
                                          RW3 + (size_t)i * 20480, (float2*)msg, cap, E);
            int cnt = nb - na;
            k_agg<<<(cnt + 3) / 4, 256, 0, stream>>>((const float2*)msg, rowptr,
                                                     agg0, agg1, na, nb, cap);
        }
        k_sc<<<N, 64, 0, stream>>>(s, v, species, Wsc_s + (size_t)i * 40960,
                                   Wsc_v + (size_t)i * 40960, sc_s, sc_v, N);
        k_4mv<<<NT, 64, 0, stream>>>(agg0, agg1, Wout_s + (size_t)i * 4096,
                                     Wout_v + (size_t)i * 4096, agg0, agg1, nullptr, N);
        k_prod_s<<<NT, 64, 0, stream>>>(agg0, agg1, P0 + (size_t)i * 1920, species,
                                        Wprod_s + (size_t)i * 4096, sc_s, s, out, N, i, L);
        k_prod_v<<<NT, 64, 0, stream>>>(agg0, agg1, P1 + (size_t)i * 1280, species,
                                        Wprod_v + (size_t)i * 4096, sc_v, v, N);
    }
}